// Round 11
// baseline (76.274 us; speedup 1.0000x reference)
//
#include <hip/hip_runtime.h>
#include <math.h>

#define NL 4
#define NBATCH 16384
#define NS 5
#define ND 6
#define NH 2
#define NHD 3
#define NFF 2048
#define EPSV 1e-5f

#define ITEMS 32               // items per block -> grid 512 -> 2 blocks/CU
#define TPB 512                // 8 waves: w<4 FFN (jq=w), w>=4 attention
#define NPAIR 64               // jt-pairs (32 j's) per layer
#define ROW (NS * ND)          // 30
#define NVAL (ITEMS * ROW)     // 960
#define HROWS 80               // rows per half (16 items x 5 tokens)

typedef __fp16 v8h __attribute__((ext_vector_type(8)));
typedef __fp16 v2h __attribute__((ext_vector_type(2)));
typedef float f32x4 __attribute__((ext_vector_type(4)));

union HU8 { uint4 u; v8h h; __fp16 f[8]; };

__device__ inline unsigned pk_u32(float a, float b) {
    union { v2h h; unsigned u; } x;
    x.h = __builtin_amdgcn_cvt_pkrtz(a, b);
    return x.u;
}

// Prepacked A-fragments for v_mfma_f32_16x16x32_f16 (lane l: row=l&15,
// k-slot (g=l>>4, e=0..7); A and B use the same (g,e)->k map so the true
// internal k order cancels).  [verified passing in round 8]
__device__ __align__(16) uint4 W1A[NL * NPAIR * 64];
__device__ __align__(16) uint4 W1B[NL * NPAIR * 64];
__device__ __align__(16) uint4 W2P[NL * NPAIR * 64];

__global__ void pack_kernel(const float* __restrict__ W1,
                            const float* __restrict__ b1,
                            const float* __restrict__ W2) {
    const int TOT = NL * NPAIR * 64;  // 16384
    int idx = blockIdx.x * 256 + threadIdx.x;
    if (idx >= 3 * TOT) return;
    int arr = idx / TOT, t = idx - arr * TOT;
    int lane = t & 63, p = (t >> 6) & 63, l = t >> 12;
    int r = lane & 15, g = lane >> 4;
    HU8 o; o.u = make_uint4(0u, 0u, 0u, 0u);
    if (arr < 2) {                      // W1A (jt=2p) / W1B (jt=2p+1)
        if (g == 0) {
            int j = (2 * p + arr) * 16 + r;
#pragma unroll
            for (int e = 0; e < ND; ++e)
                o.f[e] = (__fp16)W1[(size_t)(l * NFF + j) * ND + e];
            o.f[6] = (__fp16)b1[l * NFF + j];
            o.f[7] = (__fp16)0.f;
        }
        if (arr == 0) W1A[t] = o.u; else W1B[t] = o.u;
    } else {                            // W2P
        if (r < ND) {
#pragma unroll
            for (int e = 0; e < 8; ++e) {
                int j = p * 32 + ((e < 4) ? (4 * g + e) : (16 + 4 * g + e - 4));
                o.f[e] = (__fp16)W2[(size_t)(l * ND + r) * NFF + j];
            }
        }
        W2P[t] = o.u;
    }
}

__global__ __launch_bounds__(TPB, 4) void encoder_kernel(
    const float* __restrict__ xin,
    const float* __restrict__ Wq, const float* __restrict__ bq,
    const float* __restrict__ Wk, const float* __restrict__ bk,
    const float* __restrict__ Wv, const float* __restrict__ bv,
    const float* __restrict__ Wo, const float* __restrict__ bo,
    const float* __restrict__ b2,
    const float* __restrict__ g1, const float* __restrict__ be1,
    const float* __restrict__ g2, const float* __restrict__ be2,
    const float* __restrict__ Wfc, const float* __restrict__ bfc,
    float* __restrict__ out) {
    __shared__ float xs[NVAL];                 // 3.84 KB x state (LN1 outputs)
    __shared__ float ybuf[2 * 4 * 5 * 32 * 4]; // 20.48 KB y frags (half, jq, mt, l32, 4)
    __shared__ float kvs[2 * 16 * NS * 12];    // 7.68 KB per-half k,v

    const int tid = threadIdx.x;
    const int base = blockIdx.x * ITEMS;

    if (tid < NVAL / 4)
        ((float4*)xs)[tid] = ((const float4*)(xin + (size_t)base * ROW))[tid];

    const int lane = tid & 63;
    const int w = tid >> 6;
    // FFN role (w<4)
    const int jq = w & 3;
    const int c16 = lane & 15, g = lane >> 4;
    // attention role (w>=4): 16 lanes per item group; u<5 = token threads
    const int tid2 = tid & 255;
    const int aiL = tid2 >> 4;          // 0..15 local item
    const int u = tid2 & 15;            // sub-index in item group

    v8h z8; z8 = (v8h)(__fp16)0.f;
    const f32x4 cz = {0.f, 0.f, 0.f, 0.f};

    for (int k = 0; k <= 9; ++k) {
        __syncthreads();
        if (w < 4) {
            // ================= FFN waves (slots 1..8) =================
            if (k >= 1 && k <= 8) {
                const int hf = (k - 1) & 1, lf = (k - 1) >> 1;
                const uint4* pw1a = W1A + (size_t)(lf * NPAIR + jq * 16) * 64 + lane;
                const uint4* pw1b = W1B + (size_t)(lf * NPAIR + jq * 16) * 64 + lane;
                const uint4* pw2  = W2P + (size_t)(lf * NPAIR + jq * 16) * 64 + lane;
                uint4 wpf[2][6];
#pragma unroll
                for (int pp = 0; pp < 2; ++pp) {
                    wpf[0][pp * 3 + 0] = pw1a[pp * 64];
                    wpf[0][pp * 3 + 1] = pw1b[pp * 64];
                    wpf[0][pp * 3 + 2] = pw2[pp * 64];
                }
                v8h xb[5];
#pragma unroll
                for (int mt = 0; mt < 5; ++mt) {
                    HU8 ux; ux.u = make_uint4(0u, 0u, 0u, 0u);
                    if (g == 0) {
                        int row = hf * HROWS + mt * 16 + c16;
                        const float* xp = &xs[row * ND];
                        ux.u.x = pk_u32(xp[0], xp[1]);
                        ux.u.y = pk_u32(xp[2], xp[3]);
                        ux.u.z = pk_u32(xp[4], xp[5]);
                        ux.u.w = 0x00003c00u;   // f16 {1.0, 0.0} -> bias slot k=6
                    }
                    xb[mt] = ux.h;
                }
                f32x4 y0 = cz, y1 = cz, y2 = cz, y3 = cz, y4 = cz;
                __builtin_amdgcn_s_setprio(1);
#pragma unroll
                for (int gq = 0; gq < 8; ++gq) {
                    const int cur = gq & 1, nxt = cur ^ 1;
                    if (gq < 7) {
#pragma unroll
                        for (int pp = 0; pp < 2; ++pp) {
                            int pofs = (gq * 2 + 2 + pp) * 64;
                            wpf[nxt][pp * 3 + 0] = pw1a[pofs];
                            wpf[nxt][pp * 3 + 1] = pw1b[pofs];
                            wpf[nxt][pp * 3 + 2] = pw2[pofs];
                        }
                    }
#pragma unroll
                    for (int pp = 0; pp < 2; ++pp) {
                        HU8 a1; a1.u = wpf[cur][pp * 3 + 0];
                        HU8 b1f; b1f.u = wpf[cur][pp * 3 + 1];
                        HU8 w2f; w2f.u = wpf[cur][pp * 3 + 2];
#define FFN_STEP(YREG, XB)                                                      \
                        {                                                       \
                            f32x4 h0 = __builtin_amdgcn_mfma_f32_16x16x32_f16(  \
                                a1.h, (XB), cz, 0, 0, 0);                       \
                            f32x4 h1 = __builtin_amdgcn_mfma_f32_16x16x32_f16(  \
                                b1f.h, (XB), cz, 0, 0, 0);                      \
                            HU8 hb;                                             \
                            hb.u.x = pk_u32(h0.x, h0.y);                        \
                            hb.u.y = pk_u32(h0.z, h0.w);                        \
                            hb.u.z = pk_u32(h1.x, h1.y);                        \
                            hb.u.w = pk_u32(h1.z, h1.w);                        \
                            hb.h = __builtin_elementwise_max(hb.h, z8);         \
                            YREG = __builtin_amdgcn_mfma_f32_16x16x32_f16(      \
                                w2f.h, hb.h, YREG, 0, 0, 0);                    \
                        }
                        FFN_STEP(y0, xb[0])
                        FFN_STEP(y1, xb[1])
                        FFN_STEP(y2, xb[2])
                        FFN_STEP(y3, xb[3])
                        FFN_STEP(y4, xb[4])
#undef FFN_STEP
                    }
                }
                __builtin_amdgcn_s_setprio(0);
                if (lane < 32) {       // C-frag rows 0..7 cover d=0..5
                    f32x4* yb4 = (f32x4*)ybuf;
                    int sb = ((hf * 4 + jq) * 5) * 32 + lane;
                    yb4[sb + 0 * 32] = y0;
                    yb4[sb + 1 * 32] = y1;
                    yb4[sb + 2 * 32] = y2;
                    yb4[sb + 3 * 32] = y3;
                    yb4[sb + 4 * 32] = y4;
                }
            }
        } else {
            // ================= attention waves (serial, no shuffles) =========
            if (k <= 7) {
                const int ha = k & 1, la = k >> 1;
                if (u < NS) {
                    const int ai = ha * 16 + aiL;
                    const int R = ai * NS + u;      // (item, token=u) row
                    const int hr = aiL * 5 + u;
                    const int mtR = hr >> 4, cR = hr & 15;
                    // ---- x input: la==0 raw, else LN2(l-1) fused in registers
                    float xr[ND];
                    if (la == 0) {
#pragma unroll
                        for (int e = 0; e < ND; ++e) xr[e] = xs[R * ND + e];
                    } else {
                        const int lp = la - 1;
                        float yr[ND];
#pragma unroll
                        for (int d = 0; d < ND; ++d) {
                            float s = 0.f;
#pragma unroll
                            for (int q = 0; q < 4; ++q)
                                s += ybuf[(((ha * 4 + q) * 5 + mtR) * 32 +
                                           (d >> 2) * 16 + cR) * 4 + (d & 3)];
                            yr[d] = xs[R * ND + d] + s + b2[lp * ND + d];
                        }
                        float m = 0.f;
#pragma unroll
                        for (int d = 0; d < ND; ++d) m += yr[d];
                        m *= (1.f / ND);
                        float va = 0.f;
#pragma unroll
                        for (int d = 0; d < ND; ++d) { float dv = yr[d] - m; va += dv * dv; }
                        va *= (1.f / ND);
                        float r = rsqrtf(va + EPSV);
#pragma unroll
                        for (int d = 0; d < ND; ++d)
                            xr[d] = (yr[d] - m) * r * g2[lp * ND + d] + be2[lp * ND + d];
                    }
                    // ---- qkv (full row per thread)
                    float qr[ND], kr[ND], vr[ND];
#pragma unroll
                    for (int d = 0; d < ND; ++d) {
                        float aq = bq[la * ND + d], ak = bk[la * ND + d], av = bv[la * ND + d];
#pragma unroll
                        for (int e = 0; e < ND; ++e) {
                            aq += Wq[(la * ND + d) * ND + e] * xr[e];
                            ak += Wk[(la * ND + d) * ND + e] * xr[e];
                            av += Wv[(la * ND + d) * ND + e] * xr[e];
                        }
                        qr[d] = aq; kr[d] = ak; vr[d] = av;
                    }
                    const int gb = (ha * 16 + aiL) * NS;   // item's kvs row base
#pragma unroll
                    for (int d = 0; d < ND; ++d) {
                        kvs[(gb + u) * 12 + d] = kr[d];
                        kvs[(gb + u) * 12 + 6 + d] = vr[d];
                    }
                    // same-wave LDS handoff: writes above, reads below
                    __builtin_amdgcn_wave_barrier();
                    // ---- scores/softmax/ctx per head (serial, round-8 form)
                    const float scale = 0.57735026919f;  // 1/sqrt(HD)
                    float cf[ND];
#pragma unroll
                    for (int h = 0; h < NH; ++h) {
                        float sc[NS];
                        float mx = -1e30f;
#pragma unroll
                        for (int u2 = 0; u2 < NS; ++u2) {
                            float s = 0.f;
#pragma unroll
                            for (int c = 0; c < NHD; ++c)
                                s += qr[h * NHD + c] * kvs[(gb + u2) * 12 + h * NHD + c];
                            s *= scale;
                            sc[u2] = s;
                            mx = fmaxf(mx, s);
                        }
                        float sum = 0.f;
#pragma unroll
                        for (int u2 = 0; u2 < NS; ++u2) { sc[u2] = __expf(sc[u2] - mx); sum += sc[u2]; }
                        float inv = 1.f / sum;
#pragma unroll
                        for (int c = 0; c < NHD; ++c) {
                            float cx = 0.f;
#pragma unroll
                            for (int u2 = 0; u2 < NS; ++u2)
                                cx += sc[u2] * kvs[(gb + u2) * 12 + 6 + h * NHD + c];
                            cf[h * NHD + c] = cx * inv;
                        }
                    }
                    // ---- out-proj + residual + LN1 (per-thread, full row)
                    float yo[ND];
#pragma unroll
                    for (int d = 0; d < ND; ++d) {
                        float a = bo[la * ND + d];
#pragma unroll
                        for (int e = 0; e < ND; ++e) a += Wo[(la * ND + d) * ND + e] * cf[e];
                        yo[d] = a + xr[d];
                    }
                    float m1 = 0.f;
#pragma unroll
                    for (int d = 0; d < ND; ++d) m1 += yo[d];
                    m1 *= (1.f / ND);
                    float v1 = 0.f;
#pragma unroll
                    for (int d = 0; d < ND; ++d) { float dv = yo[d] - m1; v1 += dv * dv; }
                    v1 *= (1.f / ND);
                    float r1 = rsqrtf(v1 + EPSV);
#pragma unroll
                    for (int d = 0; d < ND; ++d)
                        xs[R * ND + d] = (yo[d] - m1) * r1 * g1[la * ND + d] + be1[la * ND + d];
                }
            } else {
                // head(half=k&1) with fused final LN2 (register-only)
                const int hd = k & 1;
                if (u < 2) {
                    const int ai = hd * 16 + aiL;
                    float acc = bfc[u];
#pragma unroll
                    for (int t = 0; t < NS; ++t) {
                        const int R = ai * NS + t;
                        const int hr = aiL * 5 + t;
                        const int mtR = hr >> 4, cR = hr & 15;
                        float yr[ND];
#pragma unroll
                        for (int d = 0; d < ND; ++d) {
                            float s = 0.f;
#pragma unroll
                            for (int q = 0; q < 4; ++q)
                                s += ybuf[(((hd * 4 + q) * 5 + mtR) * 32 +
                                           (d >> 2) * 16 + cR) * 4 + (d & 3)];
                            yr[d] = xs[R * ND + d] + s + b2[3 * ND + d];
                        }
                        float m = 0.f;
#pragma unroll
                        for (int d = 0; d < ND; ++d) m += yr[d];
                        m *= (1.f / ND);
                        float va = 0.f;
#pragma unroll
                        for (int d = 0; d < ND; ++d) { float dv = yr[d] - m; va += dv * dv; }
                        va *= (1.f / ND);
                        float r = rsqrtf(va + EPSV);
#pragma unroll
                        for (int d = 0; d < ND; ++d) {
                            float xv = (yr[d] - m) * r * g2[3 * ND + d] + be2[3 * ND + d];
                            acc += Wfc[u * ROW + t * ND + d] * xv;
                        }
                    }
                    // both logits per item computed by u=0,1; combine via LDS-free
                    // pairwise exchange within the same wave using kvs scratch
                    kvs[(hd * 16 + aiL) * 12 + u] = acc;
                    __builtin_amdgcn_wave_barrier();
                    float l0 = kvs[(hd * 16 + aiL) * 12 + 0];
                    float l1 = kvs[(hd * 16 + aiL) * 12 + 1];
                    float mxv = fmaxf(l0, l1);
                    float e0 = __expf(l0 - mxv), e1 = __expf(l1 - mxv);
                    float pv = (u == 0) ? (e0 / (e0 + e1)) : (e1 / (e0 + e1));
                    out[(size_t)(base + ai) * 2 + u] = pv;
                }
            }
        }
    }
}

extern "C" void kernel_launch(void* const* d_in, const int* in_sizes, int n_in,
                              void* d_out, int out_size, void* d_ws, size_t ws_size,
                              hipStream_t stream) {
    (void)in_sizes; (void)n_in; (void)d_ws; (void)ws_size; (void)out_size;
    const float* x = (const float*)d_in[0];
    const float* Wq = (const float*)d_in[1];
    const float* bq = (const float*)d_in[2];
    const float* Wk = (const float*)d_in[3];
    const float* bk = (const float*)d_in[4];
    const float* Wv = (const float*)d_in[5];
    const float* bv = (const float*)d_in[6];
    const float* Wo = (const float*)d_in[7];
    const float* bo = (const float*)d_in[8];
    const float* W1 = (const float*)d_in[9];
    const float* b1 = (const float*)d_in[10];
    const float* W2 = (const float*)d_in[11];
    const float* b2 = (const float*)d_in[12];
    const float* g1 = (const float*)d_in[13];
    const float* be1 = (const float*)d_in[14];
    const float* g2 = (const float*)d_in[15];
    const float* be2 = (const float*)d_in[16];
    const float* Wfc = (const float*)d_in[17];
    const float* bfc = (const float*)d_in[18];
    float* out = (float*)d_out;

    const int npack = 3 * NL * NPAIR * 64;  // 49152
    hipLaunchKernelGGL(pack_kernel, dim3((npack + 255) / 256), dim3(256), 0, stream,
                       W1, b1, W2);
    hipLaunchKernelGGL(encoder_kernel, dim3(NBATCH / ITEMS), dim3(TPB), 0, stream,
                       x, Wq, bq, Wk, bk, Wv, bv, Wo, bo, b2, g1, be1, g2, be2,
                       Wfc, bfc, out);
}

// Round 12
// 75.525 us; speedup vs baseline: 1.0099x; 1.0099x over previous
//
#include <hip/hip_runtime.h>
#include <math.h>

#define NL 4
#define NBATCH 16384
#define NS 5
#define ND 6
#define NH 2
#define NHD 3
#define NFF 2048
#define EPSV 1e-5f

#define ITEMS 32               // items per block -> grid 512 -> 2 blocks/CU
#define TPB 512                // 8 waves, all do FFN; attention = 16 lanes/item
#define NPAIR 64               // jt-pairs (32 j's) per layer
#define ROW (NS * ND)          // 30
#define NVAL (ITEMS * ROW)     // 960

typedef __fp16 v8h __attribute__((ext_vector_type(8)));
typedef __fp16 v2h __attribute__((ext_vector_type(2)));
typedef float f32x4 __attribute__((ext_vector_type(4)));

union HU8 { uint4 u; v8h h; __fp16 f[8]; };

__device__ inline unsigned pk_u32(float a, float b) {
    union { v2h h; unsigned u; } x;
    x.h = __builtin_amdgcn_cvt_pkrtz(a, b);
    return x.u;
}

// Prepacked A-fragments for v_mfma_f32_16x16x32_f16 (lane l: row=l&15,
// k-slot (g=l>>4, e=0..7); A and B use the same (g,e)->k map so the true
// internal k order cancels).  [verified passing rounds 8/11]
__device__ __align__(16) uint4 W1A[NL * NPAIR * 64];
__device__ __align__(16) uint4 W1B[NL * NPAIR * 64];
__device__ __align__(16) uint4 W2P[NL * NPAIR * 64];

__global__ void pack_kernel(const float* __restrict__ W1,
                            const float* __restrict__ b1,
                            const float* __restrict__ W2) {
    const int TOT = NL * NPAIR * 64;  // 16384
    int idx = blockIdx.x * 256 + threadIdx.x;
    if (idx >= 3 * TOT) return;
    int arr = idx / TOT, t = idx - arr * TOT;
    int lane = t & 63, p = (t >> 6) & 63, l = t >> 12;
    int r = lane & 15, g = lane >> 4;
    HU8 o; o.u = make_uint4(0u, 0u, 0u, 0u);
    if (arr < 2) {                      // W1A (jt=2p) / W1B (jt=2p+1)
        if (g == 0) {
            int j = (2 * p + arr) * 16 + r;
#pragma unroll
            for (int e = 0; e < ND; ++e)
                o.f[e] = (__fp16)W1[(size_t)(l * NFF + j) * ND + e];
            o.f[6] = (__fp16)b1[l * NFF + j];
            o.f[7] = (__fp16)0.f;
        }
        if (arr == 0) W1A[t] = o.u; else W1B[t] = o.u;
    } else {                            // W2P
        if (r < ND) {
#pragma unroll
            for (int e = 0; e < 8; ++e) {
                int j = p * 32 + ((e < 4) ? (4 * g + e) : (16 + 4 * g + e - 4));
                o.f[e] = (__fp16)W2[(size_t)(l * ND + r) * NFF + j];
            }
        }
        W2P[t] = o.u;
    }
}

__global__ __launch_bounds__(TPB, 4) void encoder_kernel(
    const float* __restrict__ xin,
    const float* __restrict__ Wq, const float* __restrict__ bq,
    const float* __restrict__ Wk, const float* __restrict__ bk,
    const float* __restrict__ Wv, const float* __restrict__ bv,
    const float* __restrict__ Wo, const float* __restrict__ bo,
    const float* __restrict__ b2,
    const float* __restrict__ g1, const float* __restrict__ be1,
    const float* __restrict__ g2, const float* __restrict__ be2,
    const float* __restrict__ Wfc, const float* __restrict__ bfc,
    float* __restrict__ out) {
    __shared__ float xs[NVAL];                 // 3.84 KB x state
    __shared__ float ybuf[4 * 2 * 5 * 32 * 4]; // 20.48 KB y frags (jq, ig, mt, l32, 4)
    __shared__ float kvs[ITEMS * NS * 12];     // 7.68 KB per-item k,v
    __shared__ float cxs[ITEMS * 10 * 3];      // 3.84 KB ctx-half exchange

    const int tid = threadIdx.x;
    const int base = blockIdx.x * ITEMS;

    if (tid < NVAL / 4)
        ((float4*)xs)[tid] = ((const float4*)(xin + (size_t)base * ROW))[tid];
    __syncthreads();

    const int lane = tid & 63;
    const int w = tid >> 6;
    // FFN role: wave (jq, ig)
    const int jq = w & 3, ig = w >> 2;
    const int c16 = lane & 15, g = lane >> 4;
    // attention role: 16 lanes per item (group never crosses a wave)
    const int ai = tid >> 4;            // item 0..31
    const int u = tid & 15;             // sub-index
    const int at = u >> 1, hh = u & 1;  // token, head (valid u<10)

    v8h z8; z8 = (v8h)(__fp16)0.f;
    const f32x4 cz = {0.f, 0.f, 0.f, 0.f};

    for (int l = 0; l < NL; ++l) {
        // ---- issue first FFN weight prefetch group (independent of xs) ----
        const uint4* pw1a = W1A + (size_t)(l * NPAIR + jq * 16) * 64 + lane;
        const uint4* pw1b = W1B + (size_t)(l * NPAIR + jq * 16) * 64 + lane;
        const uint4* pw2  = W2P + (size_t)(l * NPAIR + jq * 16) * 64 + lane;
        uint4 wpf[2][6];
#pragma unroll
        for (int pp = 0; pp < 2; ++pp) {
            wpf[0][pp * 3 + 0] = pw1a[pp * 64];
            wpf[0][pp * 3 + 1] = pw1b[pp * 64];
            wpf[0][pp * 3 + 2] = pw2[pp * 64];
        }
        // =============== S1: attention (u<10: token at, head hh) ===========
        float xr[ND], qh[NHD];
        if (u < 10) {
            const int R = ai * NS + at;
#pragma unroll
            for (int e = 0; e < ND; ++e) xr[e] = xs[R * ND + e];
            float kh[NHD], vh[NHD];
#pragma unroll
            for (int c = 0; c < NHD; ++c) {
                int d = hh * NHD + c;
                float aq = bq[l * ND + d], ak = bk[l * ND + d], av = bv[l * ND + d];
#pragma unroll
                for (int e = 0; e < ND; ++e) {
                    aq += Wq[(l * ND + d) * ND + e] * xr[e];
                    ak += Wk[(l * ND + d) * ND + e] * xr[e];
                    av += Wv[(l * ND + d) * ND + e] * xr[e];
                }
                qh[c] = aq; kh[c] = ak; vh[c] = av;
            }
#pragma unroll
            for (int c = 0; c < NHD; ++c) {
                kvs[(ai * NS + at) * 12 + hh * NHD + c] = kh[c];
                kvs[(ai * NS + at) * 12 + 6 + hh * NHD + c] = vh[c];
            }
        }
        __builtin_amdgcn_wave_barrier();
        if (u < 10) {
            const float scale = 0.57735026919f;  // 1/sqrt(HD)
            float sc[NS], mx = -1e30f;
#pragma unroll
            for (int u2 = 0; u2 < NS; ++u2) {
                float s = 0.f;
#pragma unroll
                for (int c = 0; c < NHD; ++c)
                    s += qh[c] * kvs[(ai * NS + u2) * 12 + hh * NHD + c];
                s *= scale;
                sc[u2] = s;
                mx = fmaxf(mx, s);
            }
            float sum = 0.f;
#pragma unroll
            for (int u2 = 0; u2 < NS; ++u2) { sc[u2] = __expf(sc[u2] - mx); sum += sc[u2]; }
            float inv = 1.f / sum;
#pragma unroll
            for (int c = 0; c < NHD; ++c) {
                float cx = 0.f;
#pragma unroll
                for (int u2 = 0; u2 < NS; ++u2)
                    cx += sc[u2] * kvs[(ai * NS + u2) * 12 + 6 + hh * NHD + c];
                cxs[(ai * 10 + u) * 3 + c] = cx * inv;
            }
        }
        __builtin_amdgcn_wave_barrier();
        if (u < 10) {
            const int R = ai * NS + at;
            float cf[ND];
#pragma unroll
            for (int c = 0; c < NHD; ++c) {
                cf[hh * NHD + c] = cxs[(ai * 10 + u) * 3 + c];
                cf[(1 - hh) * NHD + c] = cxs[(ai * 10 + at * 2 + (1 - hh)) * 3 + c];
            }
            float yo[ND];
#pragma unroll
            for (int d = 0; d < ND; ++d) {
                float a = bo[l * ND + d];
#pragma unroll
                for (int e = 0; e < ND; ++e) a += Wo[(l * ND + d) * ND + e] * cf[e];
                yo[d] = a + xr[d];
            }
            float m1 = 0.f;
#pragma unroll
            for (int d = 0; d < ND; ++d) m1 += yo[d];
            m1 *= (1.f / ND);
            float v1 = 0.f;
#pragma unroll
            for (int d = 0; d < ND; ++d) { float dv = yo[d] - m1; v1 += dv * dv; }
            v1 *= (1.f / ND);
            float r1 = rsqrtf(v1 + EPSV);
#pragma unroll
            for (int c = 0; c < NHD; ++c) {
                int d = hh * NHD + c;
                xs[R * ND + d] = (yo[d] - m1) * r1 * g1[l * ND + d] + be1[l * ND + d];
            }
        }
        __syncthreads();   // B1: LN1-out visible to all FFN waves
        // =============== FFN: all 8 waves, r8-identical =====================
        v8h xb[5];
#pragma unroll
        for (int mt = 0; mt < 5; ++mt) {
            HU8 ux; ux.u = make_uint4(0u, 0u, 0u, 0u);
            if (g == 0) {
                int row = ig * 80 + mt * 16 + c16;
                const float* xp = &xs[row * ND];
                ux.u.x = pk_u32(xp[0], xp[1]);
                ux.u.y = pk_u32(xp[2], xp[3]);
                ux.u.z = pk_u32(xp[4], xp[5]);
                ux.u.w = 0x00003c00u;   // f16 {1.0, 0.0} -> bias slot k=6
            }
            xb[mt] = ux.h;
        }
        f32x4 y0 = cz, y1 = cz, y2 = cz, y3 = cz, y4 = cz;
        __builtin_amdgcn_s_setprio(1);
#pragma unroll
        for (int gq = 0; gq < 8; ++gq) {
            const int cur = gq & 1, nxt = cur ^ 1;
            if (gq < 7) {
#pragma unroll
                for (int pp = 0; pp < 2; ++pp) {
                    int pofs = (gq * 2 + 2 + pp) * 64;
                    wpf[nxt][pp * 3 + 0] = pw1a[pofs];
                    wpf[nxt][pp * 3 + 1] = pw1b[pofs];
                    wpf[nxt][pp * 3 + 2] = pw2[pofs];
                }
            }
#pragma unroll
            for (int pp = 0; pp < 2; ++pp) {
                HU8 a1; a1.u = wpf[cur][pp * 3 + 0];
                HU8 b1f; b1f.u = wpf[cur][pp * 3 + 1];
                HU8 w2f; w2f.u = wpf[cur][pp * 3 + 2];
#define FFN_STEP(YREG, XB)                                                      \
                {                                                               \
                    f32x4 h0 = __builtin_amdgcn_mfma_f32_16x16x32_f16(          \
                        a1.h, (XB), cz, 0, 0, 0);                               \
                    f32x4 h1 = __builtin_amdgcn_mfma_f32_16x16x32_f16(          \
                        b1f.h, (XB), cz, 0, 0, 0);                              \
                    HU8 hb;                                                     \
                    hb.u.x = pk_u32(h0.x, h0.y);                                \
                    hb.u.y = pk_u32(h0.z, h0.w);                                \
                    hb.u.z = pk_u32(h1.x, h1.y);                                \
                    hb.u.w = pk_u32(h1.z, h1.w);                                \
                    hb.h = __builtin_elementwise_max(hb.h, z8);                 \
                    YREG = __builtin_amdgcn_mfma_f32_16x16x32_f16(              \
                        w2f.h, hb.h, YREG, 0, 0, 0);                            \
                }
                FFN_STEP(y0, xb[0])
                FFN_STEP(y1, xb[1])
                FFN_STEP(y2, xb[2])
                FFN_STEP(y3, xb[3])
                FFN_STEP(y4, xb[4])
#undef FFN_STEP
            }
        }
        __builtin_amdgcn_s_setprio(0);
        if (lane < 32) {       // C-frag rows 0..7 cover d=0..5
            f32x4* yb4 = (f32x4*)ybuf;
            int sb = ((jq * 2 + ig) * 5) * 32 + lane;
            yb4[sb + 0 * 32] = y0;
            yb4[sb + 1 * 32] = y1;
            yb4[sb + 2 * 32] = y2;
            yb4[sb + 3 * 32] = y3;
            yb4[sb + 4 * 32] = y4;
        }
        __syncthreads();   // B2: ybuf visible
        // =============== LN2 (u<5: token u of item ai) ======================
        if (u < NS) {
            const int R = ai * NS + u;
            const int hr = (ai & 15) * 5 + u;
            const int mtR = hr >> 4, cR = hr & 15;
            const int igA = ai >> 4;
            float yr[ND];
#pragma unroll
            for (int d = 0; d < ND; ++d) {
                float s = 0.f;
#pragma unroll
                for (int q = 0; q < 4; ++q)
                    s += ybuf[(((q * 2 + igA) * 5 + mtR) * 32 +
                               (d >> 2) * 16 + cR) * 4 + (d & 3)];
                yr[d] = xs[R * ND + d] + s + b2[l * ND + d];
            }
            float m = 0.f;
#pragma unroll
            for (int d = 0; d < ND; ++d) m += yr[d];
            m *= (1.f / ND);
            float va = 0.f;
#pragma unroll
            for (int d = 0; d < ND; ++d) { float dv = yr[d] - m; va += dv * dv; }
            va *= (1.f / ND);
            float r = rsqrtf(va + EPSV);
#pragma unroll
            for (int d = 0; d < ND; ++d)
                xs[R * ND + d] = (yr[d] - m) * r * g2[l * ND + d] + be2[l * ND + d];
        }
        __builtin_amdgcn_wave_barrier();  // xs handoff to same-group next S1
    }
    // =============== classification head + softmax (u<2) ====================
    if (u < 2) {
        float acc = bfc[u];
#pragma unroll
        for (int v = 0; v < ROW; ++v)
            acc += Wfc[u * ROW + v] * xs[ai * ROW + v];
        cxs[(ai * 10 + u) * 3] = acc;
    }
    __builtin_amdgcn_wave_barrier();
    if (u < 2) {
        float l0 = cxs[(ai * 10 + 0) * 3];
        float l1 = cxs[(ai * 10 + 1) * 3];
        float mxv = fmaxf(l0, l1);
        float e0 = __expf(l0 - mxv), e1 = __expf(l1 - mxv);
        float pv = (u == 0) ? (e0 / (e0 + e1)) : (e1 / (e0 + e1));
        out[(size_t)(base + ai) * 2 + u] = pv;
    }
}

extern "C" void kernel_launch(void* const* d_in, const int* in_sizes, int n_in,
                              void* d_out, int out_size, void* d_ws, size_t ws_size,
                              hipStream_t stream) {
    (void)in_sizes; (void)n_in; (void)d_ws; (void)ws_size; (void)out_size;
    const float* x = (const float*)d_in[0];
    const float* Wq = (const float*)d_in[1];
    const float* bq = (const float*)d_in[2];
    const float* Wk = (const float*)d_in[3];
    const float* bk = (const float*)d_in[4];
    const float* Wv = (const float*)d_in[5];
    const float* bv = (const float*)d_in[6];
    const float* Wo = (const float*)d_in[7];
    const float* bo = (const float*)d_in[8];
    const float* W1 = (const float*)d_in[9];
    const float* b1 = (const float*)d_in[10];
    const float* W2 = (const float*)d_in[11];
    const float* b2 = (const float*)d_in[12];
    const float* g1 = (const float*)d_in[13];
    const float* be1 = (const float*)d_in[14];
    const float* g2 = (const float*)d_in[15];
    const float* be2 = (const float*)d_in[16];
    const float* Wfc = (const float*)d_in[17];
    const float* bfc = (const float*)d_in[18];
    float* out = (float*)d_out;

    const int npack = 3 * NL * NPAIR * 64;  // 49152
    hipLaunchKernelGGL(pack_kernel, dim3((npack + 255) / 256), dim3(256), 0, stream,
                       W1, b1, W2);
    hipLaunchKernelGGL(encoder_kernel, dim3(NBATCH / ITEMS), dim3(TPB), 0, stream,
                       x, Wq, bq, Wk, bk, Wv, bv, Wo, bo, b2, g1, be1, g2, be2,
                       Wfc, bfc, out);
}

// Round 13
// 64.401 us; speedup vs baseline: 1.1844x; 1.1727x over previous
//
#include <hip/hip_runtime.h>
#include <math.h>

#define NL 4
#define NBATCH 16384
#define NS 5
#define ND 6
#define NH 2
#define NHD 3
#define NFF 2048
#define EPSV 1e-5f

#define ITEMS 16               // items per block -> grid 1024 -> ~4 blocks/CU
#define TPB 256                // 4 waves, wave w = j-quarter jq
#define NPAIR 64               // jt-pairs (32 j's) per layer
#define ROW (NS * ND)          // 30
#define NVAL (ITEMS * ROW)     // 480

typedef __fp16 v8h __attribute__((ext_vector_type(8)));
typedef __fp16 v2h __attribute__((ext_vector_type(2)));
typedef float f32x4 __attribute__((ext_vector_type(4)));

union HU8 { uint4 u; v8h h; __fp16 f[8]; };

__device__ inline unsigned pk_u32(float a, float b) {
    union { v2h h; unsigned u; } x;
    x.h = __builtin_amdgcn_cvt_pkrtz(a, b);
    return x.u;
}

// Prepacked A-fragments for v_mfma_f32_16x16x32_f16 (lane l: row=l&15,
// k-slot (g=l>>4, e=0..7); A and B use the same (g,e)->k map so the true
// internal k order cancels).  [verified passing rounds 8/11/12]
__device__ __align__(16) uint4 W1A[NL * NPAIR * 64];
__device__ __align__(16) uint4 W1B[NL * NPAIR * 64];
__device__ __align__(16) uint4 W2P[NL * NPAIR * 64];

__global__ void pack_kernel(const float* __restrict__ W1,
                            const float* __restrict__ b1,
                            const float* __restrict__ W2) {
    const int TOT = NL * NPAIR * 64;  // 16384
    int idx = blockIdx.x * 256 + threadIdx.x;
    if (idx >= 3 * TOT) return;
    int arr = idx / TOT, t = idx - arr * TOT;
    int lane = t & 63, p = (t >> 6) & 63, l = t >> 12;
    int r = lane & 15, g = lane >> 4;
    HU8 o; o.u = make_uint4(0u, 0u, 0u, 0u);
    if (arr < 2) {                      // W1A (jt=2p) / W1B (jt=2p+1)
        if (g == 0) {
            int j = (2 * p + arr) * 16 + r;
#pragma unroll
            for (int e = 0; e < ND; ++e)
                o.f[e] = (__fp16)W1[(size_t)(l * NFF + j) * ND + e];
            o.f[6] = (__fp16)b1[l * NFF + j];
            o.f[7] = (__fp16)0.f;
        }
        if (arr == 0) W1A[t] = o.u; else W1B[t] = o.u;
    } else {                            // W2P
        if (r < ND) {
#pragma unroll
            for (int e = 0; e < 8; ++e) {
                int j = p * 32 + ((e < 4) ? (4 * g + e) : (16 + 4 * g + e - 4));
                o.f[e] = (__fp16)W2[(size_t)(l * ND + r) * NFF + j];
            }
        }
        W2P[t] = o.u;
    }
}

__global__ __launch_bounds__(TPB, 4) void encoder_kernel(
    const float* __restrict__ xin,
    const float* __restrict__ Wq, const float* __restrict__ bq,
    const float* __restrict__ Wk, const float* __restrict__ bk,
    const float* __restrict__ Wv, const float* __restrict__ bv,
    const float* __restrict__ Wo, const float* __restrict__ bo,
    const float* __restrict__ b2,
    const float* __restrict__ g1, const float* __restrict__ be1,
    const float* __restrict__ g2, const float* __restrict__ be2,
    const float* __restrict__ Wfc, const float* __restrict__ bfc,
    float* __restrict__ out) {
    __shared__ float xs[NVAL];                 // 1.92 KB x state
    __shared__ float ybuf[4 * 5 * 32 * 4];     // 10.24 KB y frags (jq, mt, l32, 4)
    __shared__ float kvs[ITEMS * NS * 2 * ND]; // 3.84 KB k,v

    const int tid = threadIdx.x;
    const int base = blockIdx.x * ITEMS;

    if (tid < NVAL / 4)
        ((float4*)xs)[tid] = ((const float4*)(xin + (size_t)base * ROW))[tid];
    __syncthreads();

    const bool act = tid < ITEMS * NS;  // 80 attention threads: (item, token)
    const int ai = tid / NS;
    const int at = tid - ai * NS;

    // FFN wave role: wave = j-quarter jq; single 80-row M-panel (5 m-tiles)
    const int lane = tid & 63;
    const int jq = tid >> 6;
    const int c16 = lane & 15, g = lane >> 4;

    v8h z8; z8 = (v8h)(__fp16)0.f;
    const f32x4 cz = {0.f, 0.f, 0.f, 0.f};

    for (int l = 0; l < NL; ++l) {
        // ---- issue first FFN weight prefetch group (independent of xs) ----
        const uint4* pw1a = W1A + (size_t)(l * NPAIR + jq * 16) * 64 + lane;
        const uint4* pw1b = W1B + (size_t)(l * NPAIR + jq * 16) * 64 + lane;
        const uint4* pw2  = W2P + (size_t)(l * NPAIR + jq * 16) * 64 + lane;
        uint4 wpf[2][6];
#pragma unroll
        for (int pp = 0; pp < 2; ++pp) {
            wpf[0][pp * 3 + 0] = pw1a[pp * 64];
            wpf[0][pp * 3 + 1] = pw1b[pp * 64];
            wpf[0][pp * 3 + 2] = pw2[pp * 64];
        }

        // ---------------- attention: qkv ----------------
        float xr[ND], qv[ND];
        if (act) {
#pragma unroll
            for (int d = 0; d < ND; ++d) xr[d] = xs[(ai * NS + at) * ND + d];
#pragma unroll
            for (int d = 0; d < ND; ++d) {
                float aq = bq[l * ND + d], ak = bk[l * ND + d], av = bv[l * ND + d];
#pragma unroll
                for (int e = 0; e < ND; ++e) {
                    aq += Wq[(l * ND + d) * ND + e] * xr[e];
                    ak += Wk[(l * ND + d) * ND + e] * xr[e];
                    av += Wv[(l * ND + d) * ND + e] * xr[e];
                }
                qv[d] = aq;
                kvs[(ai * NS + at) * 2 * ND + d] = ak;
                kvs[(ai * NS + at) * 2 * ND + ND + d] = av;
            }
        }
        __syncthreads();
        // ---------------- attention: scores/ctx/outproj/LN1 ----------------
        if (act) {
            const float scale = 0.57735026919f;  // 1/sqrt(HD)
            float ctx[ND];
#pragma unroll
            for (int h = 0; h < NH; ++h) {
                float sc[NS];
                float mx = -1e30f;
#pragma unroll
                for (int u = 0; u < NS; ++u) {
                    float s = 0.f;
#pragma unroll
                    for (int d = 0; d < NHD; ++d)
                        s += qv[h * NHD + d] * kvs[(ai * NS + u) * 2 * ND + h * NHD + d];
                    s *= scale;
                    sc[u] = s;
                    mx = fmaxf(mx, s);
                }
                float sum = 0.f;
#pragma unroll
                for (int u = 0; u < NS; ++u) {
                    sc[u] = __expf(sc[u] - mx);
                    sum += sc[u];
                }
                float inv = 1.f / sum;
#pragma unroll
                for (int d = 0; d < NHD; ++d) {
                    float cx = 0.f;
#pragma unroll
                    for (int u = 0; u < NS; ++u)
                        cx += sc[u] * kvs[(ai * NS + u) * 2 * ND + ND + h * NHD + d];
                    ctx[h * NHD + d] = cx * inv;
                }
            }
            float yr[ND];
#pragma unroll
            for (int d = 0; d < ND; ++d) {
                float a = bo[l * ND + d];
#pragma unroll
                for (int e = 0; e < ND; ++e) a += Wo[(l * ND + d) * ND + e] * ctx[e];
                yr[d] = a + xr[d];
            }
            float m = 0.f;
#pragma unroll
            for (int d = 0; d < ND; ++d) m += yr[d];
            m *= (1.f / ND);
            float va = 0.f;
#pragma unroll
            for (int d = 0; d < ND; ++d) { float dv = yr[d] - m; va += dv * dv; }
            va *= (1.f / ND);
            float r = rsqrtf(va + EPSV);
#pragma unroll
            for (int d = 0; d < ND; ++d)
                xs[(ai * NS + at) * ND + d] =
                    (yr[d] - m) * r * g1[l * ND + d] + be1[l * ND + d];
        }
        __syncthreads();
        // ---------------- FFN: K=32 MFMA, all 4 waves, pipelined weights ----
        v8h xb[5];
#pragma unroll
        for (int mt = 0; mt < 5; ++mt) {
            HU8 ux; ux.u = make_uint4(0u, 0u, 0u, 0u);
            if (g == 0) {
                int row = mt * 16 + c16;
                const float* xp = &xs[row * ND];
                ux.u.x = pk_u32(xp[0], xp[1]);
                ux.u.y = pk_u32(xp[2], xp[3]);
                ux.u.z = pk_u32(xp[4], xp[5]);
                ux.u.w = 0x00003c00u;   // f16 {1.0, 0.0} -> bias slot k=6
            }
            xb[mt] = ux.h;
        }
        f32x4 y0 = cz, y1 = cz, y2 = cz, y3 = cz, y4 = cz;
        __builtin_amdgcn_s_setprio(1);
#pragma unroll
        for (int gq = 0; gq < 8; ++gq) {
            const int cur = gq & 1, nxt = cur ^ 1;
            if (gq < 7) {
#pragma unroll
                for (int pp = 0; pp < 2; ++pp) {
                    int pofs = (gq * 2 + 2 + pp) * 64;
                    wpf[nxt][pp * 3 + 0] = pw1a[pofs];
                    wpf[nxt][pp * 3 + 1] = pw1b[pofs];
                    wpf[nxt][pp * 3 + 2] = pw2[pofs];
                }
            }
#pragma unroll
            for (int pp = 0; pp < 2; ++pp) {
                HU8 a1; a1.u = wpf[cur][pp * 3 + 0];
                HU8 b1f; b1f.u = wpf[cur][pp * 3 + 1];
                HU8 w2f; w2f.u = wpf[cur][pp * 3 + 2];
#define FFN_STEP(YREG, XB)                                                      \
                {                                                               \
                    f32x4 h0 = __builtin_amdgcn_mfma_f32_16x16x32_f16(          \
                        a1.h, (XB), cz, 0, 0, 0);                               \
                    f32x4 h1 = __builtin_amdgcn_mfma_f32_16x16x32_f16(          \
                        b1f.h, (XB), cz, 0, 0, 0);                              \
                    HU8 hb;                                                     \
                    hb.u.x = pk_u32(h0.x, h0.y);                                \
                    hb.u.y = pk_u32(h0.z, h0.w);                                \
                    hb.u.z = pk_u32(h1.x, h1.y);                                \
                    hb.u.w = pk_u32(h1.z, h1.w);                                \
                    hb.h = __builtin_elementwise_max(hb.h, z8);                 \
                    YREG = __builtin_amdgcn_mfma_f32_16x16x32_f16(              \
                        w2f.h, hb.h, YREG, 0, 0, 0);                            \
                }
                FFN_STEP(y0, xb[0])
                FFN_STEP(y1, xb[1])
                FFN_STEP(y2, xb[2])
                FFN_STEP(y3, xb[3])
                FFN_STEP(y4, xb[4])
#undef FFN_STEP
            }
        }
        __builtin_amdgcn_s_setprio(0);
        // store C-frag rows 0..7 only (d<6): lanes < 32
        if (lane < 32) {
            f32x4* yb4 = (f32x4*)ybuf;
            int sb = (jq * 5) * 32 + lane;
            yb4[sb + 0 * 32] = y0;
            yb4[sb + 1 * 32] = y1;
            yb4[sb + 2 * 32] = y2;
            yb4[sb + 3 * 32] = y3;
            yb4[sb + 4 * 32] = y4;
        }
        __syncthreads();
        // ---------------- residual + LN2 (reduce the 4 j-quarters) ----------
        if (act) {
            int R = ai * NS + at;            // block row 0..79
            int mtR = R >> 4, cR = R & 15;
            float yr[ND];
#pragma unroll
            for (int d = 0; d < ND; ++d) {
                int gR = d >> 2, iR = d & 3;
                float s = 0.f;
#pragma unroll
                for (int q = 0; q < 4; ++q)
                    s += ybuf[((q * 5 + mtR) * 32 + gR * 16 + cR) * 4 + iR];
                yr[d] = xs[R * ND + d] + s + b2[l * ND + d];
            }
            float m = 0.f;
#pragma unroll
            for (int d = 0; d < ND; ++d) m += yr[d];
            m *= (1.f / ND);
            float va = 0.f;
#pragma unroll
            for (int d = 0; d < ND; ++d) { float dv = yr[d] - m; va += dv * dv; }
            va *= (1.f / ND);
            float r = rsqrtf(va + EPSV);
#pragma unroll
            for (int d = 0; d < ND; ++d)
                xs[R * ND + d] = (yr[d] - m) * r * g2[l * ND + d] + be2[l * ND + d];
        }
        __syncthreads();
    }
    // ---------------- classification head + softmax ----------------
    if (tid < ITEMS) {
        float l0 = bfc[0], l1 = bfc[1];
#pragma unroll
        for (int v = 0; v < ROW; ++v) {
            float xv = xs[tid * ROW + v];
            l0 += Wfc[v] * xv;
            l1 += Wfc[ROW + v] * xv;
        }
        float mx = fmaxf(l0, l1);
        float e0 = __expf(l0 - mx), e1 = __expf(l1 - mx);
        float inv = 1.f / (e0 + e1);
        out[(size_t)(base + tid) * 2 + 0] = e0 * inv;
        out[(size_t)(base + tid) * 2 + 1] = e1 * inv;
    }
}

extern "C" void kernel_launch(void* const* d_in, const int* in_sizes, int n_in,
                              void* d_out, int out_size, void* d_ws, size_t ws_size,
                              hipStream_t stream) {
    (void)in_sizes; (void)n_in; (void)d_ws; (void)ws_size; (void)out_size;
    const float* x = (const float*)d_in[0];
    const float* Wq = (const float*)d_in[1];
    const float* bq = (const float*)d_in[2];
    const float* Wk = (const float*)d_in[3];
    const float* bk = (const float*)d_in[4];
    const float* Wv = (const float*)d_in[5];
    const float* bv = (const float*)d_in[6];
    const float* Wo = (const float*)d_in[7];
    const float* bo = (const float*)d_in[8];
    const float* W1 = (const float*)d_in[9];
    const float* b1 = (const float*)d_in[10];
    const float* W2 = (const float*)d_in[11];
    const float* b2 = (const float*)d_in[12];
    const float* g1 = (const float*)d_in[13];
    const float* be1 = (const float*)d_in[14];
    const float* g2 = (const float*)d_in[15];
    const float* be2 = (const float*)d_in[16];
    const float* Wfc = (const float*)d_in[17];
    const float* bfc = (const float*)d_in[18];
    float* out = (float*)d_out;

    const int npack = 3 * NL * NPAIR * 64;  // 49152
    hipLaunchKernelGGL(pack_kernel, dim3((npack + 255) / 256), dim3(256), 0, stream,
                       W1, b1, W2);
    hipLaunchKernelGGL(encoder_kernel, dim3(NBATCH / ITEMS), dim3(TPB), 0, stream,
                       x, Wq, bq, Wk, bk, Wv, bv, Wo, bo, b2, g1, be1, g2, be2,
                       Wfc, bfc, out);
}